// Round 1
// baseline (2640.960 us; speedup 1.0000x reference)
//
#include <hip/hip_runtime.h>

// ---------------------------------------------------------------------------
// GCN 5-layer forward on MI355X.
//
// Identity used: spmm(edge_w, src, dst, h @ W) == spmm(edge_w, src, dst, h) @ W
// (spmm is a linear operator over rows). Per layer we run spmm on the
// narrower side:
//   L1: agg = spmm(x) [N x 256]; h1 = relu(agg @ W1 + b1)   [N x 512]
//   L2: t = h1 @ W2 [N x 256];   h2 = relu(spmm(t) + b2)
//   L3: t = h2 @ W3 [N x 128];   h3 = relu(spmm(t) + b3)
//   L4: t = h3 @ W4 [N x 64];    h4 = relu(spmm(t) + b4)
//   L5: t = h4 @ W5 [N x 64];    out = spmm(t) + b5
//
// spmm is done via a per-call CSR build (histogram + scan + scatter of packed
// (w, src) records sorted by dst), then a gather kernel: one lane-group per
// dst row, bias+relu fused. No float atomics anywhere.
// ---------------------------------------------------------------------------

// ---------------- CSR build ----------------

__global__ __launch_bounds__(256) void hist_kernel(const int* __restrict__ dst,
                                                   int* __restrict__ deg, int E) {
    int e = blockIdx.x * 256 + threadIdx.x;
    if (e < E) atomicAdd(&deg[dst[e]], 1);
}

// Single-block exclusive scan of deg[0..n) -> rowptr[0..n] and pos[0..n)
// (deg and pos are the SAME buffer: read deg, overwrite with exclusive scan).
__global__ __launch_bounds__(1024) void scan_kernel(int* deg_pos, int* rowptr, int n) {
    __shared__ int sh[1024];
    __shared__ int carry;
    if (threadIdx.x == 0) carry = 0;
    __syncthreads();
    for (int base = 0; base < n; base += 1024) {
        int i = base + threadIdx.x;
        int v = (i < n) ? deg_pos[i] : 0;
        sh[threadIdx.x] = v;
        __syncthreads();
        for (int off = 1; off < 1024; off <<= 1) {
            int t = (threadIdx.x >= off) ? sh[threadIdx.x - off] : 0;
            __syncthreads();
            sh[threadIdx.x] += t;
            __syncthreads();
        }
        int excl  = carry + sh[threadIdx.x] - v;   // exclusive prefix
        int total = sh[1023];                      // block total (all read)
        if (i < n) { rowptr[i] = excl; deg_pos[i] = excl; }
        __syncthreads();                            // all reads of carry/sh done
        if (threadIdx.x == 0) carry += total;
        __syncthreads();
    }
    if (threadIdx.x == 0) rowptr[n] = carry;
}

// Scatter edges into CSR order: erec[p] = (edge_w, src) packed 8B.
__global__ __launch_bounds__(256) void scatter_kernel(const int* __restrict__ src,
                                                      const int* __restrict__ dst,
                                                      const float* __restrict__ ew,
                                                      int* pos,
                                                      float2* __restrict__ erec, int E) {
    int e = blockIdx.x * 256 + threadIdx.x;
    if (e >= E) return;
    int p = atomicAdd(&pos[dst[e]], 1);
    erec[p] = make_float2(ew[e], __int_as_float(src[e]));
}

// ---------------- SpMM gather (CSR) ----------------
// One group of LPR = FAN/4 lanes per dst row; each lane owns one float4 of
// the feature dim. bias (nullable) + relu fused.

template <int FAN>
__global__ __launch_bounds__(256) void spmm_gather(const float* __restrict__ T,
                                                   const int* __restrict__ rowptr,
                                                   const float2* __restrict__ erec,
                                                   const float* __restrict__ bias,
                                                   float* __restrict__ out,
                                                   int N, int doRelu) {
    constexpr int LPR = FAN / 4;
    int g    = blockIdx.x * 256 + threadIdx.x;
    int row  = g / LPR;
    int lane = g % LPR;
    if (row >= N) return;
    int beg = rowptr[row];
    int end = rowptr[row + 1];
    float4 acc = make_float4(0.f, 0.f, 0.f, 0.f);
    for (int p = beg; p < end; ++p) {
        float2 rec = erec[p];
        float  w   = rec.x;
        int    s   = __float_as_int(rec.y);
        float4 v   = *reinterpret_cast<const float4*>(T + (size_t)s * FAN + lane * 4);
        acc.x = fmaf(w, v.x, acc.x);
        acc.y = fmaf(w, v.y, acc.y);
        acc.z = fmaf(w, v.z, acc.z);
        acc.w = fmaf(w, v.w, acc.w);
    }
    if (bias) {
        float4 b = *reinterpret_cast<const float4*>(bias + lane * 4);
        acc.x += b.x; acc.y += b.y; acc.z += b.z; acc.w += b.w;
    }
    if (doRelu) {
        acc.x = fmaxf(acc.x, 0.f); acc.y = fmaxf(acc.y, 0.f);
        acc.z = fmaxf(acc.z, 0.f); acc.w = fmaxf(acc.w, 0.f);
    }
    *reinterpret_cast<float4*>(out + (size_t)row * FAN + lane * 4) = acc;
}

// ---------------- Dense GEMM: C[N,M] = A[N,K] @ W[K,M] (+bias, relu) -------
// BM=128 rows/block, BN cols/block, BK=16; 256 threads; TM=8 x TN microtile.

template <int BN, int TN>
__global__ __launch_bounds__(256) void gemm_kernel(const float* __restrict__ A,
                                                   const float* __restrict__ W,
                                                   const float* __restrict__ bias,
                                                   float* __restrict__ C,
                                                   int N, int K, int M,
                                                   int doBias, int doRelu) {
    constexpr int BM = 128, BK = 16, TM = 8;
    __shared__ float As[BK][BM + 4];
    __shared__ float Ws[BK][BN + 4];
    const int tid  = threadIdx.x;
    const int tx   = tid & 15;   // 16 col-groups
    const int ty   = tid >> 4;   // 16 row-groups
    const int row0 = blockIdx.x * BM;
    const int col0 = blockIdx.y * BN;

    float acc[TM][TN];
#pragma unroll
    for (int i = 0; i < TM; ++i)
#pragma unroll
        for (int j = 0; j < TN; ++j) acc[i][j] = 0.f;

    for (int k0 = 0; k0 < K; k0 += BK) {
        // A tile: 128x16 = 512 float4, 2 per thread, stored transposed.
#pragma unroll
        for (int i = 0; i < 2; ++i) {
            int t  = tid + i * 256;
            int m  = t >> 2;
            int k4 = (t & 3) << 2;
            int r  = row0 + m;
            float4 v = make_float4(0.f, 0.f, 0.f, 0.f);
            if (r < N) v = *reinterpret_cast<const float4*>(A + (size_t)r * K + k0 + k4);
            As[k4 + 0][m] = v.x; As[k4 + 1][m] = v.y;
            As[k4 + 2][m] = v.z; As[k4 + 3][m] = v.w;
        }
        // W tile: 16xBN
        constexpr int WF4 = BK * BN / 4;
#pragma unroll
        for (int i = 0; i < WF4 / 256; ++i) {
            int t  = tid + i * 256;
            int kk = t / (BN / 4);
            int n4 = (t % (BN / 4)) << 2;
            float4 v = *reinterpret_cast<const float4*>(W + (size_t)(k0 + kk) * M + col0 + n4);
            Ws[kk][n4 + 0] = v.x; Ws[kk][n4 + 1] = v.y;
            Ws[kk][n4 + 2] = v.z; Ws[kk][n4 + 3] = v.w;
        }
        __syncthreads();
#pragma unroll
        for (int kk = 0; kk < BK; ++kk) {
            float a[TM], b[TN];
#pragma unroll
            for (int i = 0; i < TM; ++i) a[i] = As[kk][ty * TM + i];
#pragma unroll
            for (int j = 0; j < TN; ++j) b[j] = Ws[kk][tx * TN + j];
#pragma unroll
            for (int i = 0; i < TM; ++i)
#pragma unroll
                for (int j = 0; j < TN; ++j) acc[i][j] = fmaf(a[i], b[j], acc[i][j]);
        }
        __syncthreads();
    }

#pragma unroll
    for (int i = 0; i < TM; ++i) {
        int r = row0 + ty * TM + i;
        if (r >= N) continue;
#pragma unroll
        for (int j4 = 0; j4 < TN; j4 += 4) {
            int c = col0 + tx * TN + j4;
            float4 v = make_float4(acc[i][j4], acc[i][j4 + 1], acc[i][j4 + 2], acc[i][j4 + 3]);
            if (doBias) {
                v.x += bias[c]; v.y += bias[c + 1]; v.z += bias[c + 2]; v.w += bias[c + 3];
            }
            if (doRelu) {
                v.x = fmaxf(v.x, 0.f); v.y = fmaxf(v.y, 0.f);
                v.z = fmaxf(v.z, 0.f); v.w = fmaxf(v.w, 0.f);
            }
            *reinterpret_cast<float4*>(C + (size_t)r * M + c) = v;
        }
    }
}

// ---------------------------------------------------------------------------

extern "C" void kernel_launch(void* const* d_in, const int* in_sizes, int n_in,
                              void* d_out, int out_size, void* d_ws, size_t ws_size,
                              hipStream_t stream) {
    const float* x   = (const float*)d_in[0];
    const int*   src = (const int*)d_in[1];
    const int*   dst = (const int*)d_in[2];
    const float* ew  = (const float*)d_in[3];
    const float* W1  = (const float*)d_in[4];  const float* b1 = (const float*)d_in[5];
    const float* W2  = (const float*)d_in[6];  const float* b2 = (const float*)d_in[7];
    const float* W3  = (const float*)d_in[8];  const float* b3 = (const float*)d_in[9];
    const float* W4  = (const float*)d_in[10]; const float* b4 = (const float*)d_in[11];
    const float* W5  = (const float*)d_in[12]; const float* b5 = (const float*)d_in[13];

    const int N = in_sizes[0] / 256;  // 100000
    const int E = in_sizes[1];        // 3200000

    // Workspace carve-up (~334 MB total)
    char*  ws   = (char*)d_ws;
    size_t off  = 0;
    float* bufA = (float*)(ws + off); off += (size_t)N * 512 * 4;  // h buffers (max N x 512)
    float* bufB = (float*)(ws + off); off += (size_t)N * 256 * 4;  // t buffers (max N x 256)
    int* rowptr = (int*)(ws + off);   off += ((size_t)N + 1) * 4;
    int* pos    = (int*)(ws + off);   off += (size_t)N * 4;
    off = (off + 7) & ~(size_t)7;
    float2* erec = (float2*)(ws + off);  // E * 8 bytes
    (void)ws_size; (void)n_in; (void)out_size;

    // ---- CSR build (once per call) ----
    hipMemsetAsync(pos, 0, (size_t)N * 4, stream);
    hist_kernel<<<(E + 255) / 256, 256, 0, stream>>>(dst, pos, E);
    scan_kernel<<<1, 1024, 0, stream>>>(pos, rowptr, N);
    scatter_kernel<<<(E + 255) / 256, 256, 0, stream>>>(src, dst, ew, pos, erec, E);

    // ---- Layer 1: agg = spmm(x) [N,256]; h1 = relu(agg@W1 + b1) [N,512] ----
    spmm_gather<256><<<((size_t)N * 64 + 255) / 256, 256, 0, stream>>>(
        x, rowptr, erec, nullptr, bufB, N, 0);
    {
        dim3 g((N + 127) / 128, 512 / 128);
        gemm_kernel<128, 8><<<g, 256, 0, stream>>>(bufB, W1, b1, bufA, N, 256, 512, 1, 1);
    }
    // ---- Layer 2: t = h1@W2 [N,256]; h2 = relu(spmm(t)+b2) ----
    {
        dim3 g((N + 127) / 128, 256 / 128);
        gemm_kernel<128, 8><<<g, 256, 0, stream>>>(bufA, W2, nullptr, bufB, N, 512, 256, 0, 0);
    }
    spmm_gather<256><<<((size_t)N * 64 + 255) / 256, 256, 0, stream>>>(
        bufB, rowptr, erec, b2, bufA, N, 1);
    // ---- Layer 3: t = h2@W3 [N,128]; h3 = relu(spmm(t)+b3) ----
    {
        dim3 g((N + 127) / 128, 1);
        gemm_kernel<128, 8><<<g, 256, 0, stream>>>(bufA, W3, nullptr, bufB, N, 256, 128, 0, 0);
    }
    spmm_gather<128><<<((size_t)N * 32 + 255) / 256, 256, 0, stream>>>(
        bufB, rowptr, erec, b3, bufA, N, 1);
    // ---- Layer 4: t = h3@W4 [N,64]; h4 = relu(spmm(t)+b4) ----
    {
        dim3 g((N + 127) / 128, 1);
        gemm_kernel<64, 4><<<g, 256, 0, stream>>>(bufA, W4, nullptr, bufB, N, 128, 64, 0, 0);
    }
    spmm_gather<64><<<((size_t)N * 16 + 255) / 256, 256, 0, stream>>>(
        bufB, rowptr, erec, b4, bufA, N, 1);
    // ---- Layer 5: t = h4@W5 [N,64]; out = spmm(t)+b5 (no relu) ----
    {
        dim3 g((N + 127) / 128, 1);
        gemm_kernel<64, 4><<<g, 256, 0, stream>>>(bufA, W5, nullptr, bufB, N, 64, 64, 0, 0);
    }
    spmm_gather<64><<<((size_t)N * 16 + 255) / 256, 256, 0, stream>>>(
        bufB, rowptr, erec, b5, (float*)d_out, N, 0);
}

// Round 2
// 1446.267 us; speedup vs baseline: 1.8261x; 1.8261x over previous
//
#include <hip/hip_runtime.h>

// ---------------------------------------------------------------------------
// GCN 5-layer forward, bf16 edition.
//   spmm(edge_w, src, dst, h @ W) == spmm(edge_w, src, dst, h) @ W
//   L1: agg = spmm(x_bf16) [N,256]; h1 = relu(agg@W1 + b1)  (bias/relu in GEMM)
//   L2..L5: t = h@W (MFMA bf16); h' = spmm(t) + b (+relu except L5)
// All feature matrices stored bf16 (halves gather traffic); accum fp32.
// GEMM: mfma_f32_16x16x32_bf16, 128x{128,64} tile, 4 waves, XOR-swizzled LDS.
// ---------------------------------------------------------------------------

typedef __attribute__((ext_vector_type(8))) short short8;
typedef __attribute__((ext_vector_type(4))) float f32x4;

__device__ __forceinline__ ushort f2bf(float f) {
    unsigned u = __float_as_uint(f);
    u += 0x7FFFu + ((u >> 16) & 1u);   // RNE
    return (ushort)(u >> 16);
}
__device__ __forceinline__ float bfl(unsigned u) { return __uint_as_float(u << 16); }
__device__ __forceinline__ float bfh(unsigned u) { return __uint_as_float(u & 0xFFFF0000u); }

// ---------------- CSR build ----------------

__global__ __launch_bounds__(256) void hist_kernel(const int* __restrict__ dst,
                                                   int* __restrict__ deg, int E) {
    int e = blockIdx.x * 256 + threadIdx.x;
    if (e < E) atomicAdd(&deg[dst[e]], 1);
}

__global__ __launch_bounds__(1024) void scan_kernel(int* deg_pos, int* rowptr, int n) {
    __shared__ int sh[1024];
    __shared__ int carry;
    if (threadIdx.x == 0) carry = 0;
    __syncthreads();
    for (int base = 0; base < n; base += 1024) {
        int i = base + threadIdx.x;
        int v = (i < n) ? deg_pos[i] : 0;
        sh[threadIdx.x] = v;
        __syncthreads();
        for (int off = 1; off < 1024; off <<= 1) {
            int t = (threadIdx.x >= off) ? sh[threadIdx.x - off] : 0;
            __syncthreads();
            sh[threadIdx.x] += t;
            __syncthreads();
        }
        int excl  = carry + sh[threadIdx.x] - v;
        int total = sh[1023];
        if (i < n) { rowptr[i] = excl; deg_pos[i] = excl; }
        __syncthreads();
        if (threadIdx.x == 0) carry += total;
        __syncthreads();
    }
    if (threadIdx.x == 0) rowptr[n] = carry;
}

__global__ __launch_bounds__(256) void scatter_kernel(const int* __restrict__ src,
                                                      const int* __restrict__ dst,
                                                      const float* __restrict__ ew,
                                                      int* pos,
                                                      float2* __restrict__ erec, int E) {
    int e = blockIdx.x * 256 + threadIdx.x;
    if (e >= E) return;
    int p = atomicAdd(&pos[dst[e]], 1);
    erec[p] = make_float2(ew[e], __int_as_float(src[e]));
}

// ---------------- conversions ----------------

__global__ __launch_bounds__(256) void convert_x_kernel(const float* __restrict__ in,
                                                        ushort* __restrict__ out, int n4) {
    int i = blockIdx.x * 256 + threadIdx.x;
    if (i >= n4) return;
    float4 v = reinterpret_cast<const float4*>(in)[i];
    uint2 o;
    o.x = ((unsigned)f2bf(v.y) << 16) | (unsigned)f2bf(v.x);
    o.y = ((unsigned)f2bf(v.w) << 16) | (unsigned)f2bf(v.z);
    reinterpret_cast<uint2*>(out)[i] = o;
}

// W [K][M] fp32 -> WT [M][K] bf16
__global__ __launch_bounds__(256) void convert_wt_kernel(const float* __restrict__ W,
                                                         ushort* __restrict__ WT,
                                                         int K, int M) {
    int i = blockIdx.x * 256 + threadIdx.x;
    if (i >= K * M) return;
    int k = i / M, m = i - k * M;
    WT[(size_t)m * K + k] = f2bf(W[i]);
}

// ---------------- SpMM gather (CSR, bf16 payload) ----------------
// One group of LPR = FAN/8 lanes per dst row; lane owns 8 bf16 (16 B).

template <int FAN, bool OUTF32>
__global__ __launch_bounds__(256) void spmm_gather_bf(
        const ushort* __restrict__ T, const int* __restrict__ rowptr,
        const float2* __restrict__ erec, const float* __restrict__ bias,
        void* __restrict__ outp, int N, int doRelu) {
    constexpr int LPR = FAN / 8;
    int g = blockIdx.x * 256 + threadIdx.x;
    int row = g / LPR;
    int lane = g - row * LPR;
    if (row >= N) return;
    const int beg = rowptr[row];
    const int end = rowptr[row + 1];
    float acc[8];
#pragma unroll
    for (int j = 0; j < 8; ++j) acc[j] = 0.0f;

    const ushort* Tl = T + lane * 8;
    int p = beg;
    for (; p + 2 <= end; p += 2) {
        float2 e0 = erec[p];
        float2 e1 = erec[p + 1];
        uint4 v0 = *reinterpret_cast<const uint4*>(Tl + (size_t)__float_as_int(e0.y) * FAN);
        uint4 v1 = *reinterpret_cast<const uint4*>(Tl + (size_t)__float_as_int(e1.y) * FAN);
        float w0 = e0.x, w1 = e1.x;
        acc[0] = fmaf(w0, bfl(v0.x), acc[0]);
        acc[1] = fmaf(w0, bfh(v0.x), acc[1]);
        acc[2] = fmaf(w0, bfl(v0.y), acc[2]);
        acc[3] = fmaf(w0, bfh(v0.y), acc[3]);
        acc[4] = fmaf(w0, bfl(v0.z), acc[4]);
        acc[5] = fmaf(w0, bfh(v0.z), acc[5]);
        acc[6] = fmaf(w0, bfl(v0.w), acc[6]);
        acc[7] = fmaf(w0, bfh(v0.w), acc[7]);
        acc[0] = fmaf(w1, bfl(v1.x), acc[0]);
        acc[1] = fmaf(w1, bfh(v1.x), acc[1]);
        acc[2] = fmaf(w1, bfl(v1.y), acc[2]);
        acc[3] = fmaf(w1, bfh(v1.y), acc[3]);
        acc[4] = fmaf(w1, bfl(v1.z), acc[4]);
        acc[5] = fmaf(w1, bfh(v1.z), acc[5]);
        acc[6] = fmaf(w1, bfl(v1.w), acc[6]);
        acc[7] = fmaf(w1, bfh(v1.w), acc[7]);
    }
    if (p < end) {
        float2 e0 = erec[p];
        uint4 v0 = *reinterpret_cast<const uint4*>(Tl + (size_t)__float_as_int(e0.y) * FAN);
        float w0 = e0.x;
        acc[0] = fmaf(w0, bfl(v0.x), acc[0]);
        acc[1] = fmaf(w0, bfh(v0.x), acc[1]);
        acc[2] = fmaf(w0, bfl(v0.y), acc[2]);
        acc[3] = fmaf(w0, bfh(v0.y), acc[3]);
        acc[4] = fmaf(w0, bfl(v0.z), acc[4]);
        acc[5] = fmaf(w0, bfh(v0.z), acc[5]);
        acc[6] = fmaf(w0, bfl(v0.w), acc[6]);
        acc[7] = fmaf(w0, bfh(v0.w), acc[7]);
    }
    if (bias != nullptr) {
#pragma unroll
        for (int j = 0; j < 8; ++j) acc[j] += bias[lane * 8 + j];
    }
    if (doRelu) {
#pragma unroll
        for (int j = 0; j < 8; ++j) acc[j] = fmaxf(acc[j], 0.0f);
    }
    if (OUTF32) {
        float* o = (float*)outp + (size_t)row * FAN + lane * 8;
        float4 f0 = make_float4(acc[0], acc[1], acc[2], acc[3]);
        float4 f1 = make_float4(acc[4], acc[5], acc[6], acc[7]);
        *reinterpret_cast<float4*>(o) = f0;
        *reinterpret_cast<float4*>(o + 4) = f1;
    } else {
        uint4 u;
        u.x = ((unsigned)f2bf(acc[1]) << 16) | (unsigned)f2bf(acc[0]);
        u.y = ((unsigned)f2bf(acc[3]) << 16) | (unsigned)f2bf(acc[2]);
        u.z = ((unsigned)f2bf(acc[5]) << 16) | (unsigned)f2bf(acc[4]);
        u.w = ((unsigned)f2bf(acc[7]) << 16) | (unsigned)f2bf(acc[6]);
        *reinterpret_cast<uint4*>((ushort*)outp + (size_t)row * FAN + lane * 8) = u;
    }
}

// ---------------- bf16 MFMA GEMM: C[N,M] = A[N,K] @ W[K,M] ----------------
// A row-major bf16 [Npad][K]; BT = W^T row-major bf16 [M][K]; C bf16 [Npad][M].
// BM=128, BK=32, 256 threads = 4 waves (WM x WN). XOR chunk swizzle on LDS.

template <int BN, int WM, int WN>
__global__ __launch_bounds__(256) void gemm_mfma(const ushort* __restrict__ A,
                                                 const ushort* __restrict__ BT,
                                                 const float* __restrict__ bias,
                                                 ushort* __restrict__ C,
                                                 int N, int K, int M, int doBiasRelu) {
    constexpr int BM = 128, BK = 32;
    constexpr int WROWS = BM / WM;
    constexpr int WCOLS = BN / WN;
    constexpr int MR = WROWS / 16;
    constexpr int NR = WCOLS / 16;
    __shared__ ushort As[BM][BK];
    __shared__ ushort Bs[BN][BK];

    const int tid  = threadIdx.x;
    const int wid  = tid >> 6;
    const int lane = tid & 63;
    const int l16  = lane & 15;
    const int lq   = lane >> 4;
    const int wr   = wid / WN;
    const int wc   = wid % WN;
    const long row0 = (long)blockIdx.x * BM;
    const int  col0 = blockIdx.y * BN;

    f32x4 acc[MR][NR] = {};

    for (int k0 = 0; k0 < K; k0 += BK) {
        // stage A tile: BM x BK bf16 = 512 chunks of 16 B, 2 per thread
#pragma unroll
        for (int i = 0; i < (BM * BK / 8) / 256; ++i) {
            int t = tid + i * 256;
            int r = t >> 2;
            int c = t & 3;
            uint4 v = *reinterpret_cast<const uint4*>(A + (row0 + r) * K + k0 + c * 8);
            *reinterpret_cast<uint4*>(&As[r][(c ^ (r & 3)) * 8]) = v;
        }
        // stage B tile: BN x BK
#pragma unroll
        for (int i = 0; i < (BN * BK / 8) / 256; ++i) {
            int t = tid + i * 256;
            int r = t >> 2;
            int c = t & 3;
            uint4 v = *reinterpret_cast<const uint4*>(BT + (size_t)(col0 + r) * K + k0 + c * 8);
            *reinterpret_cast<uint4*>(&Bs[r][(c ^ (r & 3)) * 8]) = v;
        }
        __syncthreads();

        short8 af[MR], bf[NR];
#pragma unroll
        for (int m = 0; m < MR; ++m) {
            int r = wr * WROWS + m * 16 + l16;
            af[m] = *reinterpret_cast<const short8*>(&As[r][(lq ^ (l16 & 3)) * 8]);
        }
#pragma unroll
        for (int n = 0; n < NR; ++n) {
            int r = wc * WCOLS + n * 16 + l16;
            bf[n] = *reinterpret_cast<const short8*>(&Bs[r][(lq ^ (l16 & 3)) * 8]);
        }
#pragma unroll
        for (int m = 0; m < MR; ++m)
#pragma unroll
            for (int n = 0; n < NR; ++n)
                acc[m][n] = __builtin_amdgcn_mfma_f32_16x16x32_bf16(af[m], bf[n], acc[m][n], 0, 0, 0);
        __syncthreads();
    }

    // epilogue: C/D layout (m89): col = lane&15, row = (lane>>4)*4 + reg
#pragma unroll
    for (int m = 0; m < MR; ++m) {
#pragma unroll
        for (int n = 0; n < NR; ++n) {
            int gcol = col0 + wc * WCOLS + n * 16 + l16;
            float bb = doBiasRelu ? bias[gcol] : 0.0f;
#pragma unroll
            for (int r = 0; r < 4; ++r) {
                long grow = row0 + wr * WROWS + m * 16 + lq * 4 + r;
                if (grow < N) {
                    float f = acc[m][n][r] + bb;
                    if (doBiasRelu) f = fmaxf(f, 0.0f);
                    C[grow * M + gcol] = f2bf(f);
                }
            }
        }
    }
}

// ---------------------------------------------------------------------------

extern "C" void kernel_launch(void* const* d_in, const int* in_sizes, int n_in,
                              void* d_out, int out_size, void* d_ws, size_t ws_size,
                              hipStream_t stream) {
    const float* x   = (const float*)d_in[0];
    const int*   src = (const int*)d_in[1];
    const int*   dst = (const int*)d_in[2];
    const float* ew  = (const float*)d_in[3];
    const float* W[5]  = {(const float*)d_in[4], (const float*)d_in[6], (const float*)d_in[8],
                          (const float*)d_in[10], (const float*)d_in[12]};
    const float* b[5]  = {(const float*)d_in[5], (const float*)d_in[7], (const float*)d_in[9],
                          (const float*)d_in[11], (const float*)d_in[13]};
    const int Kd[5] = {256, 512, 256, 128, 64};
    const int Md[5] = {512, 256, 128, 64, 64};

    const int N = in_sizes[0] / 256;   // 100000
    const int E = in_sizes[1];         // 3200000
    const int Npad = ((N + 127) / 128) * 128;

    // Workspace carve-up (~284 MB)
    char*  ws  = (char*)d_ws;
    size_t off = 0;
    ushort* buf0 = (ushort*)(ws + off); off += (size_t)Npad * 512 * 2;
    ushort* buf1 = (ushort*)(ws + off); off += (size_t)Npad * 512 * 2;
    ushort* xb   = (ushort*)(ws + off); off += (size_t)Npad * 256 * 2;
    int* rowptr  = (int*)(ws + off);    off += ((size_t)N + 1) * 4;
    int* pos     = (int*)(ws + off);    off += (size_t)N * 4;
    off = (off + 15) & ~(size_t)15;
    float2* erec = (float2*)(ws + off); off += (size_t)E * 8;
    ushort* WT[5];
    for (int i = 0; i < 5; ++i) { WT[i] = (ushort*)(ws + off); off += (size_t)Kd[i] * Md[i] * 2; }
    (void)ws_size; (void)n_in; (void)out_size;

    // ---- CSR build ----
    hipMemsetAsync(pos, 0, (size_t)N * 4, stream);
    hist_kernel<<<(E + 255) / 256, 256, 0, stream>>>(dst, pos, E);
    scan_kernel<<<1, 1024, 0, stream>>>(pos, rowptr, N);
    scatter_kernel<<<(E + 255) / 256, 256, 0, stream>>>(src, dst, ew, pos, erec, E);

    // ---- conversions ----
    convert_x_kernel<<<((size_t)N * 64 + 255) / 256, 256, 0, stream>>>(x, xb, N * 64);
    for (int i = 0; i < 5; ++i) {
        int n = Kd[i] * Md[i];
        convert_wt_kernel<<<(n + 255) / 256, 256, 0, stream>>>(W[i], WT[i], Kd[i], Md[i]);
    }

    // ---- Layer 1: agg = spmm(xb) [N,256]; h1 = relu(agg@W1 + b1) [N,512] ----
    spmm_gather_bf<256, false><<<((size_t)N * 32 + 255) / 256, 256, 0, stream>>>(
        xb, rowptr, erec, nullptr, buf0, N, 0);
    {
        dim3 g(Npad / 128, 512 / 128);
        gemm_mfma<128, 2, 2><<<g, 256, 0, stream>>>(buf0, WT[0], b[0], buf1, N, 256, 512, 1);
    }
    // ---- Layer 2 ----
    {
        dim3 g(Npad / 128, 256 / 128);
        gemm_mfma<128, 2, 2><<<g, 256, 0, stream>>>(buf1, WT[1], nullptr, buf0, N, 512, 256, 0);
    }
    spmm_gather_bf<256, false><<<((size_t)N * 32 + 255) / 256, 256, 0, stream>>>(
        buf0, rowptr, erec, b[1], buf1, N, 1);
    // ---- Layer 3 ----
    {
        dim3 g(Npad / 128, 1);
        gemm_mfma<128, 2, 2><<<g, 256, 0, stream>>>(buf1, WT[2], nullptr, buf0, N, 256, 128, 0);
    }
    spmm_gather_bf<128, false><<<((size_t)N * 16 + 255) / 256, 256, 0, stream>>>(
        buf0, rowptr, erec, b[2], buf1, N, 1);
    // ---- Layer 4 ----
    {
        dim3 g(Npad / 128, 1);
        gemm_mfma<64, 4, 1><<<g, 256, 0, stream>>>(buf1, WT[3], nullptr, buf0, N, 128, 64, 0);
    }
    spmm_gather_bf<64, false><<<((size_t)N * 8 + 255) / 256, 256, 0, stream>>>(
        buf0, rowptr, erec, b[3], buf1, N, 1);
    // ---- Layer 5 ----
    {
        dim3 g(Npad / 128, 1);
        gemm_mfma<64, 4, 1><<<g, 256, 0, stream>>>(buf1, WT[4], nullptr, buf0, N, 64, 64, 0);
    }
    spmm_gather_bf<64, true><<<((size_t)N * 8 + 255) / 256, 256, 0, stream>>>(
        buf0, rowptr, erec, b[4], (float*)d_out, N, 0);
}

// Round 3
// 1255.350 us; speedup vs baseline: 2.1038x; 1.1521x over previous
//
#include <hip/hip_runtime.h>

// ---------------------------------------------------------------------------
// GCN 5-layer forward, bf16 + MFMA + XCD-partitioned CSR build.
//   spmm(edge_w, src, dst, h @ W) == spmm(edge_w, src, dst, h) @ W
// Edge records packed to 4B: (src << 15) | w15  (w 15-bit fixed point).
// CSR build: partitioned hist/scatter, range = blockIdx%8 pins each dst-range
// to one XCD so pos-window and erec-window stay L2-resident and private.
// ---------------------------------------------------------------------------

typedef __attribute__((ext_vector_type(8))) short short8;
typedef __attribute__((ext_vector_type(4))) float f32x4;

__device__ __forceinline__ ushort f2bf(float f) {
    unsigned u = __float_as_uint(f);
    u += 0x7FFFu + ((u >> 16) & 1u);   // RNE
    return (ushort)(u >> 16);
}
__device__ __forceinline__ float bfl(unsigned u) { return __uint_as_float(u << 16); }
__device__ __forceinline__ float bfh(unsigned u) { return __uint_as_float(u & 0xFFFF0000u); }

#define RANGES 8
#define EPB 16384

// ---------------- CSR build (partitioned) ----------------

__global__ __launch_bounds__(256) void hist_part(const int* __restrict__ dst,
                                                 int* __restrict__ deg,
                                                 int E, int rspan) {
    int range = blockIdx.x & (RANGES - 1);
    int chunk = blockIdx.x / RANGES;
    int lo = range * rspan;
    int base = chunk * EPB;
    int lim = base + EPB < E ? base + EPB : E;
    for (int e = base + (int)threadIdx.x; e < lim; e += 256) {
        int d = dst[e];
        if (d >= lo && d < lo + rspan) atomicAdd(&deg[d], 1);
    }
}

__global__ __launch_bounds__(256) void scatter_part(const int* __restrict__ src,
                                                    const int* __restrict__ dst,
                                                    const float* __restrict__ ew,
                                                    int* pos,
                                                    unsigned* __restrict__ erec,
                                                    int E, int rspan) {
    int range = blockIdx.x & (RANGES - 1);
    int chunk = blockIdx.x / RANGES;
    int lo = range * rspan;
    int base = chunk * EPB;
    int lim = base + EPB < E ? base + EPB : E;
    for (int e = base + (int)threadIdx.x; e < lim; e += 256) {
        int d = dst[e];
        if (d >= lo && d < lo + rspan) {
            int p = atomicAdd(&pos[d], 1);
            float w = ew[e];
            unsigned w15 = (unsigned)(w * 32768.0f + 0.5f);
            if (w15 > 32767u) w15 = 32767u;
            erec[p] = ((unsigned)src[e] << 15) | w15;
        }
    }
}

// 3-phase scan: per-block sums -> scan sums (1 block) -> block-local + offset
__global__ __launch_bounds__(256) void scan_p1(const int* __restrict__ deg,
                                               int* __restrict__ sums, int n) {
    int i = blockIdx.x * 256 + threadIdx.x;
    int v = (i < n) ? deg[i] : 0;
    for (int off = 32; off > 0; off >>= 1) v += __shfl_down(v, off, 64);
    __shared__ int ws[4];
    if ((threadIdx.x & 63) == 0) ws[threadIdx.x >> 6] = v;
    __syncthreads();
    if (threadIdx.x == 0) sums[blockIdx.x] = ws[0] + ws[1] + ws[2] + ws[3];
}

__global__ __launch_bounds__(512) void scan_p2(int* __restrict__ sums,
                                               int* __restrict__ rowptr, int n, int nb) {
    __shared__ int sh[512];
    int v = ((int)threadIdx.x < nb) ? sums[threadIdx.x] : 0;
    sh[threadIdx.x] = v;
    __syncthreads();
    for (int off = 1; off < 512; off <<= 1) {
        int t = ((int)threadIdx.x >= off) ? sh[threadIdx.x - off] : 0;
        __syncthreads();
        sh[threadIdx.x] += t;
        __syncthreads();
    }
    if ((int)threadIdx.x < nb) sums[threadIdx.x] = sh[threadIdx.x] - v;  // exclusive
    if (threadIdx.x == 0) rowptr[n] = sh[511];                          // grand total
}

__global__ __launch_bounds__(256) void scan_p3(const int* __restrict__ deg,
                                               const int* __restrict__ sums,
                                               int* __restrict__ rowptr,
                                               int* __restrict__ pos, int n) {
    __shared__ int sh[256];
    int i = blockIdx.x * 256 + threadIdx.x;
    int v = (i < n) ? deg[i] : 0;
    sh[threadIdx.x] = v;
    __syncthreads();
    for (int off = 1; off < 256; off <<= 1) {
        int t = ((int)threadIdx.x >= off) ? sh[threadIdx.x - off] : 0;
        __syncthreads();
        sh[threadIdx.x] += t;
        __syncthreads();
    }
    int excl = sums[blockIdx.x] + sh[threadIdx.x] - v;
    if (i < n) { rowptr[i] = excl; pos[i] = excl; }
}

// ---------------- conversions ----------------

__global__ __launch_bounds__(256) void convert_x_kernel(const float* __restrict__ in,
                                                        ushort* __restrict__ out, int n4) {
    int i = blockIdx.x * 256 + threadIdx.x;
    if (i >= n4) return;
    float4 v = reinterpret_cast<const float4*>(in)[i];
    uint2 o;
    o.x = ((unsigned)f2bf(v.y) << 16) | (unsigned)f2bf(v.x);
    o.y = ((unsigned)f2bf(v.w) << 16) | (unsigned)f2bf(v.z);
    reinterpret_cast<uint2*>(out)[i] = o;
}

// W [K][M] fp32 -> WT [M][K] bf16
__global__ __launch_bounds__(256) void convert_wt_kernel(const float* __restrict__ W,
                                                         ushort* __restrict__ WT,
                                                         int K, int M) {
    int i = blockIdx.x * 256 + threadIdx.x;
    if (i >= K * M) return;
    int k = i / M, m = i - k * M;
    WT[(size_t)m * K + k] = f2bf(W[i]);
}

// ---------------- SpMM gather (CSR, bf16 payload, 4B records) ----------------

#define EDGE_FMA(r, v)                                            \
    {                                                             \
        float w = (float)((r) & 32767u) * (1.0f / 32768.0f);      \
        acc[0] = fmaf(w, bfl((v).x), acc[0]);                     \
        acc[1] = fmaf(w, bfh((v).x), acc[1]);                     \
        acc[2] = fmaf(w, bfl((v).y), acc[2]);                     \
        acc[3] = fmaf(w, bfh((v).y), acc[3]);                     \
        acc[4] = fmaf(w, bfl((v).z), acc[4]);                     \
        acc[5] = fmaf(w, bfh((v).z), acc[5]);                     \
        acc[6] = fmaf(w, bfl((v).w), acc[6]);                     \
        acc[7] = fmaf(w, bfh((v).w), acc[7]);                     \
    }

template <int FAN, bool OUTF32>
__global__ __launch_bounds__(256) void spmm_gather_bf(
        const ushort* __restrict__ T, const int* __restrict__ rowptr,
        const unsigned* __restrict__ erec, const float* __restrict__ bias,
        void* __restrict__ outp, int N, int doRelu) {
    constexpr int LPR = FAN / 8;
    int g = blockIdx.x * 256 + threadIdx.x;
    int row = g / LPR;
    int lane = g - row * LPR;
    if (row >= N) return;
    const int beg = rowptr[row];
    const int end = rowptr[row + 1];
    float acc[8];
#pragma unroll
    for (int j = 0; j < 8; ++j) acc[j] = 0.0f;

    const ushort* Tl = T + lane * 8;
    int p = beg;
    for (; p + 4 <= end; p += 4) {
        unsigned r0 = erec[p], r1 = erec[p + 1], r2 = erec[p + 2], r3 = erec[p + 3];
        uint4 v0 = *reinterpret_cast<const uint4*>(Tl + (size_t)(r0 >> 15) * FAN);
        uint4 v1 = *reinterpret_cast<const uint4*>(Tl + (size_t)(r1 >> 15) * FAN);
        uint4 v2 = *reinterpret_cast<const uint4*>(Tl + (size_t)(r2 >> 15) * FAN);
        uint4 v3 = *reinterpret_cast<const uint4*>(Tl + (size_t)(r3 >> 15) * FAN);
        EDGE_FMA(r0, v0);
        EDGE_FMA(r1, v1);
        EDGE_FMA(r2, v2);
        EDGE_FMA(r3, v3);
    }
    for (; p < end; ++p) {
        unsigned r0 = erec[p];
        uint4 v0 = *reinterpret_cast<const uint4*>(Tl + (size_t)(r0 >> 15) * FAN);
        EDGE_FMA(r0, v0);
    }
    if (bias != nullptr) {
#pragma unroll
        for (int j = 0; j < 8; ++j) acc[j] += bias[lane * 8 + j];
    }
    if (doRelu) {
#pragma unroll
        for (int j = 0; j < 8; ++j) acc[j] = fmaxf(acc[j], 0.0f);
    }
    if (OUTF32) {
        float* o = (float*)outp + (size_t)row * FAN + lane * 8;
        *reinterpret_cast<float4*>(o)     = make_float4(acc[0], acc[1], acc[2], acc[3]);
        *reinterpret_cast<float4*>(o + 4) = make_float4(acc[4], acc[5], acc[6], acc[7]);
    } else {
        uint4 u;
        u.x = ((unsigned)f2bf(acc[1]) << 16) | (unsigned)f2bf(acc[0]);
        u.y = ((unsigned)f2bf(acc[3]) << 16) | (unsigned)f2bf(acc[2]);
        u.z = ((unsigned)f2bf(acc[5]) << 16) | (unsigned)f2bf(acc[4]);
        u.w = ((unsigned)f2bf(acc[7]) << 16) | (unsigned)f2bf(acc[6]);
        *reinterpret_cast<uint4*>((ushort*)outp + (size_t)row * FAN + lane * 8) = u;
    }
}

// ---------------- bf16 MFMA GEMM: C[N,M] = A[N,K] @ W[K,M] ----------------

template <int BN, int WM, int WN>
__global__ __launch_bounds__(256) void gemm_mfma(const ushort* __restrict__ A,
                                                 const ushort* __restrict__ BT,
                                                 const float* __restrict__ bias,
                                                 ushort* __restrict__ C,
                                                 int N, int K, int M, int doBiasRelu) {
    constexpr int BM = 128, BK = 32;
    constexpr int WROWS = BM / WM;
    constexpr int WCOLS = BN / WN;
    constexpr int MR = WROWS / 16;
    constexpr int NR = WCOLS / 16;
    __shared__ ushort As[BM][BK];
    __shared__ ushort Bs[BN][BK];

    const int tid  = threadIdx.x;
    const int wid  = tid >> 6;
    const int lane = tid & 63;
    const int l16  = lane & 15;
    const int lq   = lane >> 4;
    const int wr   = wid / WN;
    const int wc   = wid % WN;
    const long row0 = (long)blockIdx.x * BM;
    const int  col0 = blockIdx.y * BN;

    f32x4 acc[MR][NR] = {};

    for (int k0 = 0; k0 < K; k0 += BK) {
#pragma unroll
        for (int i = 0; i < (BM * BK / 8) / 256; ++i) {
            int t = tid + i * 256;
            int r = t >> 2;
            int c = t & 3;
            uint4 v = *reinterpret_cast<const uint4*>(A + (row0 + r) * K + k0 + c * 8);
            *reinterpret_cast<uint4*>(&As[r][(c ^ (r & 3)) * 8]) = v;
        }
#pragma unroll
        for (int i = 0; i < (BN * BK / 8) / 256; ++i) {
            int t = tid + i * 256;
            int r = t >> 2;
            int c = t & 3;
            uint4 v = *reinterpret_cast<const uint4*>(BT + (size_t)(col0 + r) * K + k0 + c * 8);
            *reinterpret_cast<uint4*>(&Bs[r][(c ^ (r & 3)) * 8]) = v;
        }
        __syncthreads();

        short8 af[MR], bf[NR];
#pragma unroll
        for (int m = 0; m < MR; ++m) {
            int r = wr * WROWS + m * 16 + l16;
            af[m] = *reinterpret_cast<const short8*>(&As[r][(lq ^ (l16 & 3)) * 8]);
        }
#pragma unroll
        for (int n = 0; n < NR; ++n) {
            int r = wc * WCOLS + n * 16 + l16;
            bf[n] = *reinterpret_cast<const short8*>(&Bs[r][(lq ^ (l16 & 3)) * 8]);
        }
#pragma unroll
        for (int m = 0; m < MR; ++m)
#pragma unroll
            for (int n = 0; n < NR; ++n)
                acc[m][n] = __builtin_amdgcn_mfma_f32_16x16x32_bf16(af[m], bf[n], acc[m][n], 0, 0, 0);
        __syncthreads();
    }

    // C/D layout: col = lane&15, row = (lane>>4)*4 + reg
#pragma unroll
    for (int m = 0; m < MR; ++m) {
#pragma unroll
        for (int n = 0; n < NR; ++n) {
            int gcol = col0 + wc * WCOLS + n * 16 + l16;
            float bb = doBiasRelu ? bias[gcol] : 0.0f;
#pragma unroll
            for (int r = 0; r < 4; ++r) {
                long grow = row0 + wr * WROWS + m * 16 + lq * 4 + r;
                if (grow < N) {
                    float f = acc[m][n][r] + bb;
                    if (doBiasRelu) f = fmaxf(f, 0.0f);
                    C[grow * M + gcol] = f2bf(f);
                }
            }
        }
    }
}

// ---------------------------------------------------------------------------

extern "C" void kernel_launch(void* const* d_in, const int* in_sizes, int n_in,
                              void* d_out, int out_size, void* d_ws, size_t ws_size,
                              hipStream_t stream) {
    const float* x   = (const float*)d_in[0];
    const int*   src = (const int*)d_in[1];
    const int*   dst = (const int*)d_in[2];
    const float* ew  = (const float*)d_in[3];
    const float* W[5]  = {(const float*)d_in[4], (const float*)d_in[6], (const float*)d_in[8],
                          (const float*)d_in[10], (const float*)d_in[12]};
    const float* b[5]  = {(const float*)d_in[5], (const float*)d_in[7], (const float*)d_in[9],
                          (const float*)d_in[11], (const float*)d_in[13]};
    const int Kd[5] = {256, 512, 256, 128, 64};
    const int Md[5] = {512, 256, 128, 64, 64};

    const int N = in_sizes[0] / 256;   // 100000
    const int E = in_sizes[1];         // 3200000
    const int Npad = ((N + 127) / 128) * 128;
    const int nb = (N + 255) / 256;    // scan blocks (391 <= 512)

    // Workspace carve-up (~271 MB)
    char*  ws  = (char*)d_ws;
    size_t off = 0;
    ushort* buf0 = (ushort*)(ws + off); off += (size_t)Npad * 512 * 2;
    ushort* buf1 = (ushort*)(ws + off); off += (size_t)Npad * 512 * 2;
    ushort* xb   = (ushort*)(ws + off); off += (size_t)Npad * 256 * 2;
    int* rowptr  = (int*)(ws + off);    off += ((size_t)N + 1) * 4;
    int* deg     = (int*)(ws + off);    off += (size_t)N * 4;
    int* pos     = (int*)(ws + off);    off += (size_t)N * 4;
    int* sums    = (int*)(ws + off);    off += 512 * 4;
    off = (off + 15) & ~(size_t)15;
    unsigned* erec = (unsigned*)(ws + off); off += (size_t)E * 4;
    ushort* WT[5];
    for (int i = 0; i < 5; ++i) { WT[i] = (ushort*)(ws + off); off += (size_t)Kd[i] * Md[i] * 2; }
    (void)ws_size; (void)n_in; (void)out_size;

    const int nchunks = (E + EPB - 1) / EPB;
    const int rspan   = (N + RANGES - 1) / RANGES;

    // ---- CSR build ----
    hipMemsetAsync(deg, 0, (size_t)N * 4, stream);
    hist_part<<<RANGES * nchunks, 256, 0, stream>>>(dst, deg, E, rspan);
    scan_p1<<<nb, 256, 0, stream>>>(deg, sums, N);
    scan_p2<<<1, 512, 0, stream>>>(sums, rowptr, N, nb);
    scan_p3<<<nb, 256, 0, stream>>>(deg, sums, rowptr, pos, N);
    scatter_part<<<RANGES * nchunks, 256, 0, stream>>>(src, dst, ew, pos, erec, E, rspan);

    // ---- conversions ----
    convert_x_kernel<<<((size_t)N * 64 + 255) / 256, 256, 0, stream>>>(x, xb, N * 64);
    for (int i = 0; i < 5; ++i) {
        int n = Kd[i] * Md[i];
        convert_wt_kernel<<<(n + 255) / 256, 256, 0, stream>>>(W[i], WT[i], Kd[i], Md[i]);
    }

    // ---- Layer 1: agg = spmm(xb) [N,256]; h1 = relu(agg@W1 + b1) [N,512] ----
    spmm_gather_bf<256, false><<<((size_t)N * 32 + 255) / 256, 256, 0, stream>>>(
        xb, rowptr, erec, nullptr, buf0, N, 0);
    {
        dim3 g(Npad / 128, 512 / 128);
        gemm_mfma<128, 2, 2><<<g, 256, 0, stream>>>(buf0, WT[0], b[0], buf1, N, 256, 512, 1);
    }
    // ---- Layer 2 ----
    {
        dim3 g(Npad / 128, 256 / 128);
        gemm_mfma<128, 2, 2><<<g, 256, 0, stream>>>(buf1, WT[1], nullptr, buf0, N, 512, 256, 0);
    }
    spmm_gather_bf<256, false><<<((size_t)N * 32 + 255) / 256, 256, 0, stream>>>(
        buf0, rowptr, erec, b[1], buf1, N, 1);
    // ---- Layer 3 ----
    {
        dim3 g(Npad / 128, 1);
        gemm_mfma<128, 2, 2><<<g, 256, 0, stream>>>(buf1, WT[2], nullptr, buf0, N, 256, 128, 0);
    }
    spmm_gather_bf<128, false><<<((size_t)N * 16 + 255) / 256, 256, 0, stream>>>(
        buf0, rowptr, erec, b[2], buf1, N, 1);
    // ---- Layer 4 ----
    {
        dim3 g(Npad / 128, 1);
        gemm_mfma<64, 4, 1><<<g, 256, 0, stream>>>(buf1, WT[3], nullptr, buf0, N, 128, 64, 0);
    }
    spmm_gather_bf<64, false><<<((size_t)N * 8 + 255) / 256, 256, 0, stream>>>(
        buf0, rowptr, erec, b[3], buf1, N, 1);
    // ---- Layer 5 ----
    {
        dim3 g(Npad / 128, 1);
        gemm_mfma<64, 4, 1><<<g, 256, 0, stream>>>(buf1, WT[4], nullptr, buf0, N, 64, 64, 0);
    }
    spmm_gather_bf<64, true><<<((size_t)N * 8 + 255) / 256, 256, 0, stream>>>(
        buf0, rowptr, erec, b[4], (float*)d_out, N, 0);
}

// Round 4
// 1211.040 us; speedup vs baseline: 2.1807x; 1.0366x over previous
//
#include <hip/hip_runtime.h>

// ---------------------------------------------------------------------------
// GCN 5-layer forward, bf16 + MFMA(global_load_lds) + XCD-partitioned CSR.
//   spmm(edge_w, src, dst, h @ W) == spmm(edge_w, src, dst, h) @ W
// Edge records 4B: (src << 15) | w15. Gathers are at structural traffic floor
// (~3.3 TB/s TCC-miss, 54% L2 hit); this round optimizes GEMM + prologue.
// GEMM: BK=64, global_load_lds width16, G21 both-sides XOR swizzle (r&7).
// ---------------------------------------------------------------------------

typedef __attribute__((ext_vector_type(8))) short short8;
typedef __attribute__((ext_vector_type(4))) float f32x4;

__device__ __forceinline__ ushort f2bf(float f) {
    unsigned u = __float_as_uint(f);
    u += 0x7FFFu + ((u >> 16) & 1u);   // RNE
    return (ushort)(u >> 16);
}
__device__ __forceinline__ float bfl(unsigned u) { return __uint_as_float(u << 16); }
__device__ __forceinline__ float bfh(unsigned u) { return __uint_as_float(u & 0xFFFF0000u); }

__device__ __forceinline__ void gl_lds16(const void* g, void* l) {
    __builtin_amdgcn_global_load_lds(
        (const __attribute__((address_space(1))) unsigned*)g,
        (__attribute__((address_space(3))) unsigned*)l, 16, 0, 0);
}

#define RANGES 8
#define EPB 16384
#define HB 2048      // hist blocks in prologue

// ---------------- fused prologue: hist + convert_x + convert W1..W5 --------

__global__ __launch_bounds__(256) void prologue_kernel(
        const int* __restrict__ dst, int* __restrict__ deg, int E,
        const float* __restrict__ x, ushort* __restrict__ xb, int n4,
        const float* W1, const float* W2, const float* W3, const float* W4, const float* W5,
        ushort* T1, ushort* T2, ushort* T3, ushort* T4, ushort* T5) {
    int bid = blockIdx.x;
    if (bid < HB) {
        for (int e = bid * 256 + (int)threadIdx.x; e < E; e += HB * 256)
            atomicAdd(&deg[dst[e]], 1);
        return;
    }
    bid -= HB;
    int XB = (n4 + 255) / 256;
    if (bid < XB) {
        int i = bid * 256 + threadIdx.x;
        if (i >= n4) return;
        float4 v = reinterpret_cast<const float4*>(x)[i];
        uint2 o;
        o.x = ((unsigned)f2bf(v.y) << 16) | (unsigned)f2bf(v.x);
        o.y = ((unsigned)f2bf(v.w) << 16) | (unsigned)f2bf(v.z);
        reinterpret_cast<uint2*>(xb)[i] = o;
        return;
    }
    bid -= XB;
    int i = bid * 256 + threadIdx.x;   // flat weight index over 307200
    const float* W; ushort* T; int K, M, base;
    if      (i < 131072) { W = W1; T = T1; K = 256; M = 512; base = 0; }
    else if (i < 262144) { W = W2; T = T2; K = 512; M = 256; base = 131072; }
    else if (i < 294912) { W = W3; T = T3; K = 256; M = 128; base = 262144; }
    else if (i < 303104) { W = W4; T = T4; K = 128; M = 64;  base = 294912; }
    else if (i < 307200) { W = W5; T = T5; K = 64;  M = 64;  base = 303104; }
    else return;
    int l = i - base;
    int k = l / M, m = l - k * M;
    T[(size_t)m * K + k] = f2bf(W[l]);
}

// ---------------- CSR scan + partitioned scatter ----------------

__global__ __launch_bounds__(256) void scan_p1(const int* __restrict__ deg,
                                               int* __restrict__ sums, int n) {
    int i = blockIdx.x * 256 + threadIdx.x;
    int v = (i < n) ? deg[i] : 0;
    for (int off = 32; off > 0; off >>= 1) v += __shfl_down(v, off, 64);
    __shared__ int ws[4];
    if ((threadIdx.x & 63) == 0) ws[threadIdx.x >> 6] = v;
    __syncthreads();
    if (threadIdx.x == 0) sums[blockIdx.x] = ws[0] + ws[1] + ws[2] + ws[3];
}

__global__ __launch_bounds__(512) void scan_p2(int* __restrict__ sums,
                                               int* __restrict__ rowptr, int n, int nb) {
    __shared__ int sh[512];
    int v = ((int)threadIdx.x < nb) ? sums[threadIdx.x] : 0;
    sh[threadIdx.x] = v;
    __syncthreads();
    for (int off = 1; off < 512; off <<= 1) {
        int t = ((int)threadIdx.x >= off) ? sh[threadIdx.x - off] : 0;
        __syncthreads();
        sh[threadIdx.x] += t;
        __syncthreads();
    }
    if ((int)threadIdx.x < nb) sums[threadIdx.x] = sh[threadIdx.x] - v;  // exclusive
    if (threadIdx.x == 0) rowptr[n] = sh[511];
}

__global__ __launch_bounds__(256) void scan_p3(const int* __restrict__ deg,
                                               const int* __restrict__ sums,
                                               int* __restrict__ rowptr,
                                               int* __restrict__ pos, int n) {
    __shared__ int sh[256];
    int i = blockIdx.x * 256 + threadIdx.x;
    int v = (i < n) ? deg[i] : 0;
    sh[threadIdx.x] = v;
    __syncthreads();
    for (int off = 1; off < 256; off <<= 1) {
        int t = ((int)threadIdx.x >= off) ? sh[threadIdx.x - off] : 0;
        __syncthreads();
        sh[threadIdx.x] += t;
        __syncthreads();
    }
    int excl = sums[blockIdx.x] + sh[threadIdx.x] - v;
    if (i < n) { rowptr[i] = excl; pos[i] = excl; }
}

__global__ __launch_bounds__(256) void scatter_part(const int* __restrict__ src,
                                                    const int* __restrict__ dst,
                                                    const float* __restrict__ ew,
                                                    int* pos,
                                                    unsigned* __restrict__ erec,
                                                    int E, int rspan) {
    int range = blockIdx.x & (RANGES - 1);
    int chunk = blockIdx.x / RANGES;
    int lo = range * rspan;
    int base = chunk * EPB;
    int lim = base + EPB < E ? base + EPB : E;
    for (int e = base + (int)threadIdx.x; e < lim; e += 256) {
        int d = dst[e];
        if (d >= lo && d < lo + rspan) {
            int p = atomicAdd(&pos[d], 1);
            float w = ew[e];
            unsigned w15 = (unsigned)(w * 32768.0f + 0.5f);
            if (w15 > 32767u) w15 = 32767u;
            erec[p] = ((unsigned)src[e] << 15) | w15;
        }
    }
}

// ---------------- SpMM gather (CSR, bf16 payload, 4B records) ----------------

#define EDGE_FMA(r, v)                                            \
    {                                                             \
        float w = (float)((r) & 32767u) * (1.0f / 32768.0f);      \
        acc[0] = fmaf(w, bfl((v).x), acc[0]);                     \
        acc[1] = fmaf(w, bfh((v).x), acc[1]);                     \
        acc[2] = fmaf(w, bfl((v).y), acc[2]);                     \
        acc[3] = fmaf(w, bfh((v).y), acc[3]);                     \
        acc[4] = fmaf(w, bfl((v).z), acc[4]);                     \
        acc[5] = fmaf(w, bfh((v).z), acc[5]);                     \
        acc[6] = fmaf(w, bfl((v).w), acc[6]);                     \
        acc[7] = fmaf(w, bfh((v).w), acc[7]);                     \
    }

template <int FAN, bool OUTF32>
__global__ __launch_bounds__(256) void spmm_gather_bf(
        const ushort* __restrict__ T, const int* __restrict__ rowptr,
        const unsigned* __restrict__ erec, const float* __restrict__ bias,
        void* __restrict__ outp, int N, int doRelu) {
    constexpr int LPR = FAN / 8;
    int g = blockIdx.x * 256 + threadIdx.x;
    int row = g / LPR;
    int lane = g - row * LPR;
    if (row >= N) return;
    const int beg = rowptr[row];
    const int end = rowptr[row + 1];
    float acc[8];
#pragma unroll
    for (int j = 0; j < 8; ++j) acc[j] = 0.0f;

    const ushort* Tl = T + lane * 8;
    int p = beg;
    for (; p + 8 <= end; p += 8) {
        unsigned rr[8];
        uint4 vv[8];
#pragma unroll
        for (int u = 0; u < 8; ++u) rr[u] = erec[p + u];
#pragma unroll
        for (int u = 0; u < 8; ++u)
            vv[u] = *reinterpret_cast<const uint4*>(Tl + (size_t)(rr[u] >> 15) * FAN);
#pragma unroll
        for (int u = 0; u < 8; ++u) EDGE_FMA(rr[u], vv[u]);
    }
    for (; p < end; ++p) {
        unsigned r0 = erec[p];
        uint4 v0 = *reinterpret_cast<const uint4*>(Tl + (size_t)(r0 >> 15) * FAN);
        EDGE_FMA(r0, v0);
    }
    if (bias != nullptr) {
#pragma unroll
        for (int j = 0; j < 8; ++j) acc[j] += bias[lane * 8 + j];
    }
    if (doRelu) {
#pragma unroll
        for (int j = 0; j < 8; ++j) acc[j] = fmaxf(acc[j], 0.0f);
    }
    if (OUTF32) {
        float* o = (float*)outp + (size_t)row * FAN + lane * 8;
        *reinterpret_cast<float4*>(o)     = make_float4(acc[0], acc[1], acc[2], acc[3]);
        *reinterpret_cast<float4*>(o + 4) = make_float4(acc[4], acc[5], acc[6], acc[7]);
    } else {
        uint4 u;
        u.x = ((unsigned)f2bf(acc[1]) << 16) | (unsigned)f2bf(acc[0]);
        u.y = ((unsigned)f2bf(acc[3]) << 16) | (unsigned)f2bf(acc[2]);
        u.z = ((unsigned)f2bf(acc[5]) << 16) | (unsigned)f2bf(acc[4]);
        u.w = ((unsigned)f2bf(acc[7]) << 16) | (unsigned)f2bf(acc[6]);
        *reinterpret_cast<uint4*>((ushort*)outp + (size_t)row * FAN + lane * 8) = u;
    }
}

// ---------------- bf16 MFMA GEMM: C[N,M] = A[N,K] @ W[K,M] ----------------
// A bf16 [Npad][K]; BT = W^T bf16 [M][K]; C bf16 [Npad][M].
// BM=128, BK=64, 4 waves. Staging via global_load_lds(16B): linear LDS dest,
// inverse-XOR'd global source chunk (cw ^ (r&7)); reads re-apply the XOR.

template <int BN, int WM, int WN>
__global__ __launch_bounds__(256) void gemm_mfma(const ushort* __restrict__ A,
                                                 const ushort* __restrict__ BT,
                                                 const float* __restrict__ bias,
                                                 ushort* __restrict__ C,
                                                 int N, int K, int M, int doBiasRelu) {
    constexpr int BM = 128, BK = 64;
    constexpr int WROWS = BM / WM;
    constexpr int WCOLS = BN / WN;
    constexpr int MR = WROWS / 16;
    constexpr int NR = WCOLS / 16;
    constexpr int AISS = (BM * BK / 8) / 256;   // global_load_lds issues per wave (A)
    constexpr int BISS = (BN * BK / 8) / 256;   // (B)
    __shared__ ushort As[BM][BK];
    __shared__ ushort Bs[BN][BK];

    const int tid  = threadIdx.x;
    const int wid  = tid >> 6;
    const int lane = tid & 63;
    const int l16  = lane & 15;
    const int lq   = lane >> 4;
    const int wr   = wid / WN;
    const int wc   = wid % WN;
    const long row0 = (long)blockIdx.x * BM;
    const int  col0 = blockIdx.y * BN;

    f32x4 acc[MR][NR] = {};

    for (int k0 = 0; k0 < K; k0 += BK) {
        // ---- stage A: BM*BK/8 16B chunks, linear LDS, pre-swizzled source ----
#pragma unroll
        for (int j = 0; j < AISS; ++j) {
            int t  = (wid * AISS + j) * 64 + lane;
            int r  = t >> 3;
            int cw = t & 7;
            const ushort* g = A + (row0 + r) * K + k0 + ((cw ^ (r & 7)) << 3);
            gl_lds16(g, (char*)&As[0][0] + (size_t)t * 16);
        }
#pragma unroll
        for (int j = 0; j < BISS; ++j) {
            int t  = (wid * BISS + j) * 64 + lane;
            int r  = t >> 3;
            int cw = t & 7;
            const ushort* g = BT + (size_t)(col0 + r) * K + k0 + ((cw ^ (r & 7)) << 3);
            gl_lds16(g, (char*)&Bs[0][0] + (size_t)t * 16);
        }
        __syncthreads();   // compiler drains vmcnt before s_barrier

        short8 af[2][MR], bf[2][NR];
#pragma unroll
        for (int kk = 0; kk < 2; ++kk) {
#pragma unroll
            for (int m = 0; m < MR; ++m) {
                int r = wr * WROWS + m * 16 + l16;
                af[kk][m] = *reinterpret_cast<const short8*>(&As[r][((kk * 4 + lq) ^ (r & 7)) * 8]);
            }
#pragma unroll
            for (int n = 0; n < NR; ++n) {
                int r = wc * WCOLS + n * 16 + l16;
                bf[kk][n] = *reinterpret_cast<const short8*>(&Bs[r][((kk * 4 + lq) ^ (r & 7)) * 8]);
            }
        }
#pragma unroll
        for (int kk = 0; kk < 2; ++kk)
#pragma unroll
            for (int m = 0; m < MR; ++m)
#pragma unroll
                for (int n = 0; n < NR; ++n)
                    acc[m][n] = __builtin_amdgcn_mfma_f32_16x16x32_bf16(af[kk][m], bf[kk][n], acc[m][n], 0, 0, 0);
        __syncthreads();
    }

    // C/D layout: col = lane&15, row = (lane>>4)*4 + reg
#pragma unroll
    for (int m = 0; m < MR; ++m) {
#pragma unroll
        for (int n = 0; n < NR; ++n) {
            int gcol = col0 + wc * WCOLS + n * 16 + l16;
            float bb = doBiasRelu ? bias[gcol] : 0.0f;
#pragma unroll
            for (int r = 0; r < 4; ++r) {
                long grow = row0 + wr * WROWS + m * 16 + lq * 4 + r;
                if (grow < N) {
                    float f = acc[m][n][r] + bb;
                    if (doBiasRelu) f = fmaxf(f, 0.0f);
                    C[grow * M + gcol] = f2bf(f);
                }
            }
        }
    }
}

// ---------------------------------------------------------------------------

extern "C" void kernel_launch(void* const* d_in, const int* in_sizes, int n_in,
                              void* d_out, int out_size, void* d_ws, size_t ws_size,
                              hipStream_t stream) {
    const float* x   = (const float*)d_in[0];
    const int*   src = (const int*)d_in[1];
    const int*   dst = (const int*)d_in[2];
    const float* ew  = (const float*)d_in[3];
    const float* W[5]  = {(const float*)d_in[4], (const float*)d_in[6], (const float*)d_in[8],
                          (const float*)d_in[10], (const float*)d_in[12]};
    const float* b[5]  = {(const float*)d_in[5], (const float*)d_in[7], (const float*)d_in[9],
                          (const float*)d_in[11], (const float*)d_in[13]};
    const int Kd[5] = {256, 512, 256, 128, 64};
    const int Md[5] = {512, 256, 128, 64, 64};

    const int N = in_sizes[0] / 256;   // 100000
    const int E = in_sizes[1];         // 3200000
    const int Npad = ((N + 127) / 128) * 128;
    const int nb = (N + 255) / 256;    // 391 <= 512

    // Workspace carve-up (~271 MB)
    char*  ws  = (char*)d_ws;
    size_t off = 0;
    ushort* buf0 = (ushort*)(ws + off); off += (size_t)Npad * 512 * 2;
    ushort* buf1 = (ushort*)(ws + off); off += (size_t)Npad * 512 * 2;
    ushort* xb   = (ushort*)(ws + off); off += (size_t)Npad * 256 * 2;
    int* rowptr  = (int*)(ws + off);    off += ((size_t)N + 1) * 4;
    int* deg     = (int*)(ws + off);    off += (size_t)N * 4;
    int* pos     = (int*)(ws + off);    off += (size_t)N * 4;
    int* sums    = (int*)(ws + off);    off += 512 * 4;
    off = (off + 15) & ~(size_t)15;
    unsigned* erec = (unsigned*)(ws + off); off += (size_t)E * 4;
    ushort* WT[5];
    for (int i = 0; i < 5; ++i) { WT[i] = (ushort*)(ws + off); off += (size_t)Kd[i] * Md[i] * 2; }
    (void)ws_size; (void)n_in; (void)out_size;

    const int nchunks = (E + EPB - 1) / EPB;
    const int rspan   = (N + RANGES - 1) / RANGES;
    const int n4 = N * 64;
    const int XB = (n4 + 255) / 256;
    const int WB = (307200 + 255) / 256;

    // ---- prologue: hist + convert_x + convert weights (one kernel) ----
    hipMemsetAsync(deg, 0, (size_t)N * 4, stream);
    prologue_kernel<<<HB + XB + WB, 256, 0, stream>>>(
        dst, deg, E, x, xb, n4,
        W[0], W[1], W[2], W[3], W[4], WT[0], WT[1], WT[2], WT[3], WT[4]);
    scan_p1<<<nb, 256, 0, stream>>>(deg, sums, N);
    scan_p2<<<1, 512, 0, stream>>>(sums, rowptr, N, nb);
    scan_p3<<<nb, 256, 0, stream>>>(deg, sums, rowptr, pos, N);
    scatter_part<<<RANGES * nchunks, 256, 0, stream>>>(src, dst, ew, pos, erec, E, rspan);

    // ---- Layer 1: agg = spmm(xb) [N,256]; h1 = relu(agg@W1 + b1) [N,512] ----
    spmm_gather_bf<256, false><<<((size_t)N * 32 + 255) / 256, 256, 0, stream>>>(
        xb, rowptr, erec, nullptr, buf0, N, 0);
    {
        dim3 g(Npad / 128, 512 / 128);
        gemm_mfma<128, 2, 2><<<g, 256, 0, stream>>>(buf0, WT[0], b[0], buf1, N, 256, 512, 1);
    }
    // ---- Layer 2 ----
    {
        dim3 g(Npad / 128, 256 / 128);
        gemm_mfma<128, 2, 2><<<g, 256, 0, stream>>>(buf1, WT[1], nullptr, buf0, N, 512, 256, 0);
    }
    spmm_gather_bf<256, false><<<((size_t)N * 32 + 255) / 256, 256, 0, stream>>>(
        buf0, rowptr, erec, b[1], buf1, N, 1);
    // ---- Layer 3 ----
    {
        dim3 g(Npad / 128, 1);
        gemm_mfma<128, 2, 2><<<g, 256, 0, stream>>>(buf1, WT[2], nullptr, buf0, N, 256, 128, 0);
    }
    spmm_gather_bf<128, false><<<((size_t)N * 16 + 255) / 256, 256, 0, stream>>>(
        buf0, rowptr, erec, b[2], buf1, N, 1);
    // ---- Layer 4 ----
    {
        dim3 g(Npad / 128, 1);
        gemm_mfma<64, 4, 1><<<g, 256, 0, stream>>>(buf1, WT[3], nullptr, buf0, N, 128, 64, 0);
    }
    spmm_gather_bf<64, false><<<((size_t)N * 8 + 255) / 256, 256, 0, stream>>>(
        buf0, rowptr, erec, b[3], buf1, N, 1);
    // ---- Layer 5 ----
    {
        dim3 g(Npad / 128, 1);
        gemm_mfma<64, 4, 1><<<g, 256, 0, stream>>>(buf1, WT[4], nullptr, buf0, N, 64, 64, 0);
    }
    spmm_gather_bf<64, true><<<((size_t)N * 8 + 255) / 256, 256, 0, stream>>>(
        buf0, rowptr, erec, b[4], (float*)d_out, N, 0);
}